// Round 12
// baseline (361.286 us; speedup 1.0000x reference)
//
#include <hip/hip_runtime.h>
#include <hip/hip_bf16.h>

typedef __bf16 bf16_t;
typedef __bf16 bf16x8 __attribute__((ext_vector_type(8)));
typedef float f32x4 __attribute__((ext_vector_type(4)));

#define MFMA16(a, b, c) __builtin_amdgcn_mfma_f32_16x16x32_bf16((a), (b), (c), 0, 0, 0)

__device__ __forceinline__ void gl_lds16(const bf16_t* g, bf16_t* l) {
  __builtin_amdgcn_global_load_lds(
      (const __attribute__((address_space(1))) void*)g,
      (__attribute__((address_space(3))) void*)l, 16, 0, 0);
}

__device__ __forceinline__ unsigned pack_bf16(float a, float b) {
  union { bf16_t h[2]; unsigned u; } c;
  c.h[0] = (bf16_t)a; c.h[1] = (bf16_t)b;
  return c.u;
}

// B=4, T=2048, D=512, H=8, DH=64 — hardcoded
// ---------------------------------------------------------------------------
// Merged prep: blocks [0,4096) convert x -> bf16; blocks [4096,4864) transpose
// the six weight matrices (fp32 -> bf16, LDS tile, coalesced both sides).
__global__ __launch_bounds__(256) void k_prep(
    const float* __restrict__ x, bf16_t* __restrict__ x_bf,
    const float* __restrict__ Wq, const float* __restrict__ Wk,
    const float* __restrict__ Wv, const float* __restrict__ Wo,
    const float* __restrict__ W1, const float* __restrict__ W2,
    bf16_t* __restrict__ WqkvT, bf16_t* __restrict__ WoT,
    bf16_t* __restrict__ W1T, bf16_t* __restrict__ W2T) {
  __shared__ float tile[64][65];
  int bid = blockIdx.x, tid = threadIdx.x;
  if (bid < 4096) {
    int i = bid * 256 + tid;  // 4096*256 == 8192*512/4 exactly
    float4 f = ((const float4*)x)[i];
    union { bf16_t h[4]; uint2 u; } cv;
    cv.h[0] = (bf16_t)f.x; cv.h[1] = (bf16_t)f.y;
    cv.h[2] = (bf16_t)f.z; cv.h[3] = (bf16_t)f.w;
    ((uint2*)x_bf)[i] = cv.u;
    return;
  }
  int t = bid - 4096;
  const float* W; bf16_t* WT; int K, N, idx, gx;
  if (t < 64)       { W = Wq; WT = WqkvT;                      K = 512;  N = 512;  idx = t;       gx = 8;  }
  else if (t < 128) { W = Wk; WT = WqkvT + (size_t)512 * 512;  K = 512;  N = 512;  idx = t - 64;  gx = 8;  }
  else if (t < 192) { W = Wv; WT = WqkvT + (size_t)1024 * 512; K = 512;  N = 512;  idx = t - 128; gx = 8;  }
  else if (t < 256) { W = Wo; WT = WoT;                        K = 512;  N = 512;  idx = t - 192; gx = 8;  }
  else if (t < 512) { W = W1; WT = W1T;                        K = 512;  N = 2048; idx = t - 256; gx = 8;  }
  else              { W = W2; WT = W2T;                        K = 2048; N = 512;  idx = t - 512; gx = 32; }
  int bk = (idx % gx) * 64, bn = (idx / gx) * 64;
  int tx = tid & 63, ty = tid >> 6;
  for (int i = ty; i < 64; i += 4)
    tile[i][tx] = W[(size_t)(bk + i) * N + bn + tx];
  __syncthreads();
  for (int i = ty; i < 64; i += 4)
    WT[(size_t)(bn + i) * K + bk + tx] = (bf16_t)tile[tx][i];
}

// ---------------------------------------------------------------------------
// C[M][N] = A[M][K] @ Bt[N][K]^T, bf16 in, fp32 accum. 2-phase double-buffered
// global_load_lds staging.
// MODE 0: fp32 C    4: GELU poly -> bf16 C    5: fused QKV scatter where
//   Q is pre-scaled by 1/8 (exact pow2), K plain [B,H,T,DH], V in the
//   quad-permuted [B,H,DH,T] layout the attention PV step consumes.
template <int MODE, int BM>
__global__ __launch_bounds__(256) void k_gemm_bt(
    const bf16_t* __restrict__ A, const bf16_t* __restrict__ Bt,
    float* __restrict__ Cf, bf16_t* __restrict__ Cb,
    bf16_t* __restrict__ Cb2, bf16_t* __restrict__ Cb3,
    int M, int N, int K, const float* __restrict__ coef) {
  __shared__ __align__(16) bf16_t As[2][BM * 32];
  __shared__ __align__(16) bf16_t Bs[2][128 * 32];
  constexpr int NF = (BM == 128) ? 4 : 2;
  int tid = threadIdx.x;
  int lane = tid & 63, wave = tid >> 6;
  int bm = blockIdx.x * BM, bn = blockIdx.y * 128;
  int wr = (BM == 128) ? (wave >> 1) * 64 : 0;
  int wc = (BM == 128) ? (wave & 1) * 64 : wave * 32;
  int lr = lane & 15, lk = (lane >> 4) * 8;
  int srow = tid >> 2, scol = (tid & 3) * 8;

  f32x4 zero = {0.f, 0.f, 0.f, 0.f};
  f32x4 acc[4][NF];
#pragma unroll
  for (int m = 0; m < 4; ++m)
#pragma unroll
    for (int n = 0; n < NF; ++n) acc[m][n] = zero;

  const bf16_t* pA = A + (size_t)(bm + srow) * K + scol;
  const bf16_t* pB = Bt + (size_t)(bn + srow) * K + scol;

  auto STAGE = [&](int buf, int k0) {
    bf16_t* lA = &As[buf][tid * 8];
    bf16_t* lB = &Bs[buf][tid * 8];
    gl_lds16(pA + k0, lA);
    if (BM == 128) gl_lds16(pA + (size_t)64 * K + k0, lA + 2048);
    gl_lds16(pB + k0, lB);
    gl_lds16(pB + (size_t)64 * K + k0, lB + 2048);
  };

  STAGE(0, 0);
  __syncthreads();
  int buf = 0;
  for (int k0 = 0; k0 < K; k0 += 32) {
    if (k0 + 32 < K) STAGE(buf ^ 1, k0 + 32);
    bf16x8 a[4], b[NF];
#pragma unroll
    for (int m = 0; m < 4; ++m) a[m] = *(const bf16x8*)&As[buf][(wr + m * 16 + lr) * 32 + lk];
#pragma unroll
    for (int n = 0; n < NF; ++n) b[n] = *(const bf16x8*)&Bs[buf][(wc + n * 16 + lr) * 32 + lk];
    __builtin_amdgcn_s_setprio(1);
#pragma unroll
    for (int m = 0; m < 4; ++m)
#pragma unroll
      for (int n = 0; n < NF; ++n)
        acc[m][n] = MFMA16(a[m], b[n], acc[m][n]);
    __builtin_amdgcn_s_setprio(0);
    __syncthreads();
    buf ^= 1;
  }

  float c8[8];
  if (MODE == 4) {
#pragma unroll
    for (int i = 0; i < 8; ++i) c8[i] = coef[i];
  }
  int rbase = (lane >> 4) * 4;
#pragma unroll
  for (int m = 0; m < 4; ++m) {
#pragma unroll
    for (int n = 0; n < NF; ++n) {
#pragma unroll
      for (int r = 0; r < 4; ++r) {
        int gm = bm + wr + m * 16 + rbase + r;
        int gn = bn + wc + n * 16 + lr;
        float v = acc[m][n][r];
        if (MODE == 0) {
          Cf[(size_t)gm * N + gn] = v;
        } else if (MODE == 4) {
          float xx = fminf(fmaxf(v, -4.f), 4.f);
          float p = c8[0], pw = 1.f;
#pragma unroll
          for (int i = 1; i < 8; ++i) { pw *= xx; p += c8[i] * pw; }
          Cb[(size_t)gm * N + gn] = (bf16_t)p;
        } else {  // 5: fused QKV scatter with attention-ready layouts
          int mat = gn >> 9, col = gn & 511;
          int b_ = gm >> 11, t_ = gm & 2047, h_ = col >> 6, d_ = col & 63;
          if (mat == 0) {
            // Q pre-scaled by 1/sqrt(DH)=1/8: exact pow2, commutes with bf16 round
            Cb[(((size_t)b_ * 8 + h_) * 2048 + t_) * 64 + d_] = (bf16_t)(v * 0.125f);
          } else if (mat == 1) {
            // K plain [B,H,T,DH] (no LDS banks anymore -> no swizzle needed)
            Cb2[(((size_t)b_ * 8 + h_) * 2048 + t_) * 64 + d_] = (bf16_t)v;
          } else {
            // V: [dh][t] with the PV quad-permutation baked in (no XOR)
            int tw = t_ & 63;
            int j = (((tw >> 2) & 3) << 1) | ((tw >> 4) & 1);
            int phys = ((tw & 32) << 1) + (j << 3) + ((tw & 3) << 1);
            size_t e = ((((size_t)b_ * 8 + h_) * 64 + d_) * 4096 +
                        (size_t)(t_ >> 6) * 128 + phys) >> 1;
            Cb3[e] = (bf16_t)v;
          }
        }
      }
    }
  }
}

// ---------------------------------------------------------------------------
// SINGLE-PASS attention, QBLK=64, KVBLK=64, 4 waves. ZERO LDS, ZERO BARRIERS:
// each wave holds its K(kt) and V(kt) MFMA fragments in registers and
// prefetches kt+1 global->reg immediately after the last use of each set
// (issue-to-use gap ~ one kt of compute >> L2 latency; K/V tiles are L2-hot).
// Waves fully independent and self-paced. No max subtraction (poly error
// cancels in normalization — r10/r11 verified); clamp removed (T6 >= 0.145
// for all real x, provably dead in the reference too). Swapped QK^T,
// in-register softmax, P packed to bf16 A-fragments; V global layout carries
// the PV quad-permutation. Q pre-scaled by 1/8.
__global__ __launch_bounds__(256) void k_attn(
    const bf16_t* __restrict__ qb, const bf16_t* __restrict__ kb,
    const bf16_t* __restrict__ vtb, bf16_t* __restrict__ ob,
    const float* __restrict__ exp_c) {
  int tid = threadIdx.x, lane = tid & 63, wave = tid >> 6;
  int b0 = blockIdx.x;
  int bid = (b0 & 7) * 128 + (b0 >> 3);  // XCD-chunked (1024 % 8 == 0)
  int qt = bid & 31, bh = bid >> 5;
  const size_t bho = (size_t)bh * (2048 * 64);
  const bf16_t* Q = qb + bho + (size_t)qt * 64 * 64;   // pre-scaled by 1/8
  const bf16_t* Kp = kb + bho;   // plain [t][dh]
  const bf16_t* Vp = vtb + bho;  // quad-permuted [dh][t]
  int lr = lane & 15, lg = lane >> 4;

  // Q fragments (registers, whole kernel). Q is B-operand: rows = q.
  bf16x8 qa[2];
#pragma unroll
  for (int h = 0; h < 2; ++h)
    qa[h] = *(const bf16x8*)&Q[(wave * 16 + lr) * 64 + h * 32 + lg * 8];

  float ec[7];
#pragma unroll
  for (int i = 0; i < 7; ++i) ec[i] = exp_c[i];

  // register-resident K/V fragments: [2n+h] = tile row block n, dh/k half h
  bf16x8 kf[8], vf[8];
  const bf16_t* kfb = Kp + (size_t)(lr)*64 + lg * 8;          // + kt*4096 + n*1024 + h*32
  const bf16_t* vfb = Vp + (size_t)(lr)*2048 + lg * 8;        // + dd*16*2048 + kt*64 + h*32
#pragma unroll
  for (int n = 0; n < 4; ++n)
#pragma unroll
    for (int h = 0; h < 2; ++h) {
      kf[2 * n + h] = *(const bf16x8*)(kfb + n * 1024 + h * 32);
      vf[2 * n + h] = *(const bf16x8*)(vfb + (size_t)n * 16 * 2048 + h * 32);
    }

  f32x4 zero = {0.f, 0.f, 0.f, 0.f};
  f32x4 oacc[4];
#pragma unroll
  for (int n = 0; n < 4; ++n) oacc[n] = zero;
  float rsum = 0.f;

  for (int kt = 0; kt < 32; ++kt) {
    // ---- QK^T(kt) from resident kf
    f32x4 s[4];
    __builtin_amdgcn_s_setprio(1);
#pragma unroll
    for (int n = 0; n < 4; ++n)
      s[n] = MFMA16(kf[2 * n + 1], qa[1], MFMA16(kf[2 * n], qa[0], zero));
    __builtin_amdgcn_s_setprio(0);
    // ---- prefetch K(kt+1) into kf (hidden under softmax+PV)
    if (kt < 31) {
      const bf16_t* kp = kfb + (size_t)(kt + 1) * 4096;
#pragma unroll
      for (int n = 0; n < 4; ++n)
#pragma unroll
        for (int h = 0; h < 2; ++h)
          kf[2 * n + h] = *(const bf16x8*)(kp + n * 1024 + h * 32);
    }
    // ---- softmax(kt): Horner only (clamp dead: T6 >= 0.145 everywhere)
    unsigned pk[4][2];
#pragma unroll
    for (int n = 0; n < 4; ++n) {
      float pf[4];
#pragma unroll
      for (int r = 0; r < 4; ++r) {
        float xv = s[n][r];  // scores pre-scaled via Q*0.125
        float p = ec[6];
#pragma unroll
        for (int i = 5; i >= 0; --i) p = __builtin_fmaf(p, xv, ec[i]);
        rsum += p;
        pf[r] = p;
      }
      pk[n][0] = pack_bf16(pf[0], pf[1]);
      pk[n][1] = pack_bf16(pf[2], pf[3]);
    }
    union { unsigned u[4]; bf16x8 v; } pa0, pa1;
    pa0.u[0] = pk[0][0]; pa0.u[1] = pk[0][1]; pa0.u[2] = pk[1][0]; pa0.u[3] = pk[1][1];
    pa1.u[0] = pk[2][0]; pa1.u[1] = pk[2][1]; pa1.u[2] = pk[3][0]; pa1.u[3] = pk[3][1];
    // ---- PV(kt) from resident vf
    __builtin_amdgcn_s_setprio(1);
#pragma unroll
    for (int dd = 0; dd < 4; ++dd)
      oacc[dd] = MFMA16(pa1.v, vf[2 * dd + 1], MFMA16(pa0.v, vf[2 * dd], oacc[dd]));
    __builtin_amdgcn_s_setprio(0);
    // ---- prefetch V(kt+1) into vf (hidden under next QK+softmax)
    if (kt < 31) {
      const bf16_t* vp = vfb + (kt + 1) * 64;
#pragma unroll
      for (int dd = 0; dd < 4; ++dd)
#pragma unroll
        for (int h = 0; h < 2; ++h)
          vf[2 * dd + h] = *(const bf16x8*)(vp + (size_t)dd * 16 * 2048 + h * 32);
    }
  }
  rsum += __shfl_xor(rsum, 16);
  rsum += __shfl_xor(rsum, 32);
  float rs4[4];
#pragma unroll
  for (int r = 0; r < 4; ++r) rs4[r] = __shfl(rsum, lg * 4 + r);

  int b_ = bh >> 3, h_ = bh & 7;
#pragma unroll
  for (int dd = 0; dd < 4; ++dd)
#pragma unroll
    for (int r = 0; r < 4; ++r) {
      int t_ = qt * 64 + wave * 16 + lg * 4 + r;
      int d_ = dd * 16 + lr;
      float val = oacc[dd][r] / rs4[r];
      ob[(((size_t)b_ * 2048 + t_) * 8 + h_) * 64 + d_] = (bf16_t)val;
    }
}

// ---------------------------------------------------------------------------
// Fused residual + LayerNorm (replicates Newton rsqrt exactly: 3 iters from 0.5).
__global__ __launch_bounds__(256) void k_ln(
    const float* __restrict__ xa, const float* __restrict__ xb,
    const float* __restrict__ gamma, const float* __restrict__ beta,
    float* __restrict__ outf, bf16_t* __restrict__ outb) {
  int row = blockIdx.x * 4 + (threadIdx.x >> 6);
  int lane = threadIdx.x & 63;
  const float* pa = xa + (size_t)row * 512;
  const float* pb = xb + (size_t)row * 512;
  float4 a0 = ((const float4*)pa)[lane];
  float4 a1 = ((const float4*)pa)[lane + 64];
  float4 b0 = ((const float4*)pb)[lane];
  float4 b1 = ((const float4*)pb)[lane + 64];
  float x[8] = {a0.x + b0.x, a0.y + b0.y, a0.z + b0.z, a0.w + b0.w,
                a1.x + b1.x, a1.y + b1.y, a1.z + b1.z, a1.w + b1.w};
  float s = 0.f, sq = 0.f;
#pragma unroll
  for (int i = 0; i < 8; ++i) { s += x[i]; sq += x[i] * x[i]; }
#pragma unroll
  for (int off = 1; off < 64; off <<= 1) {
    s += __shfl_xor(s, off);
    sq += __shfl_xor(sq, off);
  }
  float mean = s * (1.f / 512.f);
  float var = sq * (1.f / 512.f) - mean * mean;
  float v = var + 1e-5f;
  float y = 0.5f;
#pragma unroll
  for (int it = 0; it < 3; ++it) y = y * (3.0f - v * y * y) * 0.5f;

  float4 g0 = ((const float4*)gamma)[lane];
  float4 g1 = ((const float4*)gamma)[lane + 64];
  float4 e0 = ((const float4*)beta)[lane];
  float4 e1 = ((const float4*)beta)[lane + 64];
  float o[8];
  o[0] = (x[0] - mean) * y * g0.x + e0.x;
  o[1] = (x[1] - mean) * y * g0.y + e0.y;
  o[2] = (x[2] - mean) * y * g0.z + e0.z;
  o[3] = (x[3] - mean) * y * g0.w + e0.w;
  o[4] = (x[4] - mean) * y * g1.x + e1.x;
  o[5] = (x[5] - mean) * y * g1.y + e1.y;
  o[6] = (x[6] - mean) * y * g1.z + e1.z;
  o[7] = (x[7] - mean) * y * g1.w + e1.w;
  float* po = outf + (size_t)row * 512;
  ((float4*)po)[lane]      = make_float4(o[0], o[1], o[2], o[3]);
  ((float4*)po)[lane + 64] = make_float4(o[4], o[5], o[6], o[7]);
  if (outb) {
    bf16_t* pq = outb + (size_t)row * 512;
    union { bf16_t h[4]; uint2 u; } c0, c1;
    c0.h[0] = (bf16_t)o[0]; c0.h[1] = (bf16_t)o[1]; c0.h[2] = (bf16_t)o[2]; c0.h[3] = (bf16_t)o[3];
    c1.h[0] = (bf16_t)o[4]; c1.h[1] = (bf16_t)o[5]; c1.h[2] = (bf16_t)o[6]; c1.h[3] = (bf16_t)o[7];
    ((uint2*)pq)[lane]      = c0.u;
    ((uint2*)pq)[lane + 64] = c1.u;
  }
}

// ---------------------------------------------------------------------------
extern "C" void kernel_launch(void* const* d_in, const int* in_sizes, int n_in,
                              void* d_out, int out_size, void* d_ws, size_t ws_size,
                              hipStream_t stream) {
  const float* x      = (const float*)d_in[0];
  const float* Wq     = (const float*)d_in[1];
  const float* Wk     = (const float*)d_in[2];
  const float* Wv     = (const float*)d_in[3];
  const float* Wo     = (const float*)d_in[4];
  const float* W1     = (const float*)d_in[5];
  const float* W2     = (const float*)d_in[6];
  const float* g1     = (const float*)d_in[7];
  const float* b1     = (const float*)d_in[8];
  const float* g2     = (const float*)d_in[9];
  const float* b2     = (const float*)d_in[10];
  const float* gelu_c = (const float*)d_in[11];
  const float* exp_c  = (const float*)d_in[12];

  const int M = 8192;  // B*T
  const size_t actBF = (size_t)M * 512 * 2;
  char* p = (char*)d_ws;
  auto carve = [&](size_t bytes) {
    void* r = (void*)p;
    p += (bytes + 255) & ~(size_t)255;
    return r;
  };
  bf16_t* x_bf   = (bf16_t*)carve(actBF);
  bf16_t* q_bf   = (bf16_t*)carve(actBF);
  bf16_t* k_bf   = (bf16_t*)carve(actBF);
  bf16_t* vT_bf  = (bf16_t*)carve(actBF);
  bf16_t* o_bf   = (bf16_t*)carve(actBF);
  bf16_t* h_bf   = (bf16_t*)carve(actBF);
  bf16_t* WqkvT  = (bf16_t*)carve((size_t)1536 * 512 * 2);
  bf16_t* WoT    = (bf16_t*)carve(512 * 512 * 2);
  bf16_t* W1T    = (bf16_t*)carve(512 * 2048 * 2);
  bf16_t* W2T    = (bf16_t*)carve(512 * 2048 * 2);
  bf16_t* g_bf   = (bf16_t*)carve((size_t)M * 2048 * 2);
  float*  proj   = (float*)carve((size_t)M * 512 * 4);
  float*  h_f    = (float*)carve((size_t)M * 512 * 4);
  float*  f2     = proj;  // proj dead after LN1; FFN2 output aliases it

  // merged prep: cvt (4096 blocks) + 6 transposes (768 blocks)
  k_prep<<<4864, 256, 0, stream>>>(x, x_bf, Wq, Wk, Wv, Wo, W1, W2,
                                   WqkvT, WoT, W1T, W2T);

  // fused QKV projection (Q pre-scaled; K/V in attention-ready layouts)
  k_gemm_bt<5, 128><<<dim3(64, 12), 256, 0, stream>>>(
      x_bf, WqkvT, nullptr, q_bf, k_bf, vT_bf, M, 1536, 512, nullptr);

  // attention (single pass, barrier-free, QBLK=64 -> 1024 blocks)
  k_attn<<<1024, 256, 0, stream>>>(q_bf, k_bf, vT_bf, o_bf, exp_c);

  // output projection
  k_gemm_bt<0, 64><<<dim3(128, 4), 256, 0, stream>>>(
      o_bf, WoT, proj, nullptr, nullptr, nullptr, M, 512, 512, nullptr);

  // LN1
  k_ln<<<2048, 256, 0, stream>>>(x, proj, g1, b1, h_f, h_bf);

  // FFN1: gelu(h @ W1) -> bf16
  k_gemm_bt<4, 128><<<dim3(64, 16), 256, 0, stream>>>(
      h_bf, W1T, nullptr, g_bf, nullptr, nullptr, M, 2048, 512, gelu_c);

  // FFN2
  k_gemm_bt<0, 64><<<dim3(128, 4), 256, 0, stream>>>(
      g_bf, W2T, f2, nullptr, nullptr, nullptr, M, 512, 2048, nullptr);

  // LN2
  k_ln<<<2048, 256, 0, stream>>>(h_f, f2, g2, b2, (float*)d_out, nullptr);
}

// Round 13
// 191.726 us; speedup vs baseline: 1.8844x; 1.8844x over previous
//
#include <hip/hip_runtime.h>
#include <hip/hip_bf16.h>

typedef __bf16 bf16_t;
typedef __bf16 bf16x8 __attribute__((ext_vector_type(8)));
typedef float f32x4 __attribute__((ext_vector_type(4)));

#define MFMA16(a, b, c) __builtin_amdgcn_mfma_f32_16x16x32_bf16((a), (b), (c), 0, 0, 0)

__device__ __forceinline__ void gl_lds16(const bf16_t* g, bf16_t* l) {
  __builtin_amdgcn_global_load_lds(
      (const __attribute__((address_space(1))) void*)g,
      (__attribute__((address_space(3))) void*)l, 16, 0, 0);
}

__device__ __forceinline__ unsigned pack_bf16(float a, float b) {
  union { bf16_t h[2]; unsigned u; } c;
  c.h[0] = (bf16_t)a; c.h[1] = (bf16_t)b;
  return c.u;
}

// B=4, T=2048, D=512, H=8, DH=64 — hardcoded
// ---------------------------------------------------------------------------
// Merged prep: blocks [0,4096) convert x -> bf16; blocks [4096,4864) transpose
// the six weight matrices (fp32 -> bf16, LDS tile, coalesced both sides).
__global__ __launch_bounds__(256) void k_prep(
    const float* __restrict__ x, bf16_t* __restrict__ x_bf,
    const float* __restrict__ Wq, const float* __restrict__ Wk,
    const float* __restrict__ Wv, const float* __restrict__ Wo,
    const float* __restrict__ W1, const float* __restrict__ W2,
    bf16_t* __restrict__ WqkvT, bf16_t* __restrict__ WoT,
    bf16_t* __restrict__ W1T, bf16_t* __restrict__ W2T) {
  __shared__ float tile[64][65];
  int bid = blockIdx.x, tid = threadIdx.x;
  if (bid < 4096) {
    int i = bid * 256 + tid;  // 4096*256 == 8192*512/4 exactly
    float4 f = ((const float4*)x)[i];
    union { bf16_t h[4]; uint2 u; } cv;
    cv.h[0] = (bf16_t)f.x; cv.h[1] = (bf16_t)f.y;
    cv.h[2] = (bf16_t)f.z; cv.h[3] = (bf16_t)f.w;
    ((uint2*)x_bf)[i] = cv.u;
    return;
  }
  int t = bid - 4096;
  const float* W; bf16_t* WT; int K, N, idx, gx;
  if (t < 64)       { W = Wq; WT = WqkvT;                      K = 512;  N = 512;  idx = t;       gx = 8;  }
  else if (t < 128) { W = Wk; WT = WqkvT + (size_t)512 * 512;  K = 512;  N = 512;  idx = t - 64;  gx = 8;  }
  else if (t < 192) { W = Wv; WT = WqkvT + (size_t)1024 * 512; K = 512;  N = 512;  idx = t - 128; gx = 8;  }
  else if (t < 256) { W = Wo; WT = WoT;                        K = 512;  N = 512;  idx = t - 192; gx = 8;  }
  else if (t < 512) { W = W1; WT = W1T;                        K = 512;  N = 2048; idx = t - 256; gx = 8;  }
  else              { W = W2; WT = W2T;                        K = 2048; N = 512;  idx = t - 512; gx = 32; }
  int bk = (idx % gx) * 64, bn = (idx / gx) * 64;
  int tx = tid & 63, ty = tid >> 6;
  for (int i = ty; i < 64; i += 4)
    tile[i][tx] = W[(size_t)(bk + i) * N + bn + tx];
  __syncthreads();
  for (int i = ty; i < 64; i += 4)
    WT[(size_t)(bn + i) * K + bk + tx] = (bf16_t)tile[tx][i];
}

// ---------------------------------------------------------------------------
// C[M][N] = A[M][K] @ Bt[N][K]^T, bf16 in, fp32 accum. 2-phase double-buffered
// global_load_lds staging.
// MODE 0: fp32 C    4: GELU poly -> bf16 C    5: fused QKV scatter where
//   Q is pre-scaled by 1/8 (exact pow2), K is stored pre-XOR-swizzled
//   (d' = d ^ ((t&7)<<3)) and V in the gl_lds-linear permuted layout.
template <int MODE, int BM>
__global__ __launch_bounds__(256) void k_gemm_bt(
    const bf16_t* __restrict__ A, const bf16_t* __restrict__ Bt,
    float* __restrict__ Cf, bf16_t* __restrict__ Cb,
    bf16_t* __restrict__ Cb2, bf16_t* __restrict__ Cb3,
    int M, int N, int K, const float* __restrict__ coef) {
  __shared__ __align__(16) bf16_t As[2][BM * 32];
  __shared__ __align__(16) bf16_t Bs[2][128 * 32];
  constexpr int NF = (BM == 128) ? 4 : 2;
  int tid = threadIdx.x;
  int lane = tid & 63, wave = tid >> 6;
  int bm = blockIdx.x * BM, bn = blockIdx.y * 128;
  int wr = (BM == 128) ? (wave >> 1) * 64 : 0;
  int wc = (BM == 128) ? (wave & 1) * 64 : wave * 32;
  int lr = lane & 15, lk = (lane >> 4) * 8;
  int srow = tid >> 2, scol = (tid & 3) * 8;

  f32x4 zero = {0.f, 0.f, 0.f, 0.f};
  f32x4 acc[4][NF];
#pragma unroll
  for (int m = 0; m < 4; ++m)
#pragma unroll
    for (int n = 0; n < NF; ++n) acc[m][n] = zero;

  const bf16_t* pA = A + (size_t)(bm + srow) * K + scol;
  const bf16_t* pB = Bt + (size_t)(bn + srow) * K + scol;

  auto STAGE = [&](int buf, int k0) {
    bf16_t* lA = &As[buf][tid * 8];
    bf16_t* lB = &Bs[buf][tid * 8];
    gl_lds16(pA + k0, lA);
    if (BM == 128) gl_lds16(pA + (size_t)64 * K + k0, lA + 2048);
    gl_lds16(pB + k0, lB);
    gl_lds16(pB + (size_t)64 * K + k0, lB + 2048);
  };

  STAGE(0, 0);
  __syncthreads();
  int buf = 0;
  for (int k0 = 0; k0 < K; k0 += 32) {
    if (k0 + 32 < K) STAGE(buf ^ 1, k0 + 32);
    bf16x8 a[4], b[NF];
#pragma unroll
    for (int m = 0; m < 4; ++m) a[m] = *(const bf16x8*)&As[buf][(wr + m * 16 + lr) * 32 + lk];
#pragma unroll
    for (int n = 0; n < NF; ++n) b[n] = *(const bf16x8*)&Bs[buf][(wc + n * 16 + lr) * 32 + lk];
    __builtin_amdgcn_s_setprio(1);
#pragma unroll
    for (int m = 0; m < 4; ++m)
#pragma unroll
      for (int n = 0; n < NF; ++n)
        acc[m][n] = MFMA16(a[m], b[n], acc[m][n]);
    __builtin_amdgcn_s_setprio(0);
    __syncthreads();
    buf ^= 1;
  }

  float c8[8];
  if (MODE == 4) {
#pragma unroll
    for (int i = 0; i < 8; ++i) c8[i] = coef[i];
  }
  int rbase = (lane >> 4) * 4;
#pragma unroll
  for (int m = 0; m < 4; ++m) {
#pragma unroll
    for (int n = 0; n < NF; ++n) {
#pragma unroll
      for (int r = 0; r < 4; ++r) {
        int gm = bm + wr + m * 16 + rbase + r;
        int gn = bn + wc + n * 16 + lr;
        float v = acc[m][n][r];
        if (MODE == 0) {
          Cf[(size_t)gm * N + gn] = v;
        } else if (MODE == 4) {
          float xx = fminf(fmaxf(v, -4.f), 4.f);
          float p = c8[0], pw = 1.f;
#pragma unroll
          for (int i = 1; i < 8; ++i) { pw *= xx; p += c8[i] * pw; }
          Cb[(size_t)gm * N + gn] = (bf16_t)p;
        } else {  // 5: fused QKV scatter with attention-ready layouts
          int mat = gn >> 9, col = gn & 511;
          int b_ = gm >> 11, t_ = gm & 2047, h_ = col >> 6, d_ = col & 63;
          if (mat == 0) {
            // Q pre-scaled by 1/sqrt(DH)=1/8: exact pow2, commutes with bf16 round
            Cb[(((size_t)b_ * 8 + h_) * 2048 + t_) * 64 + d_] = (bf16_t)(v * 0.125f);
          } else if (mat == 1) {
            int dsw = d_ ^ ((t_ & 7) << 3);
            Cb2[(((size_t)b_ * 8 + h_) * 2048 + t_) * 64 + dsw] = (bf16_t)v;
          } else {
            int tw = t_ & 63;
            int j = (((tw >> 2) & 3) << 1) | ((tw >> 4) & 1);
            int phys = (((tw & 32) << 1) + (j << 3) + ((tw & 3) << 1)) ^ ((d_ & 7) << 4);
            size_t e = ((((size_t)b_ * 8 + h_) * 64 + d_) * 4096 +
                        (size_t)(t_ >> 6) * 128 + phys) >> 1;
            Cb3[e] = (bf16_t)v;
          }
        }
      }
    }
  }
}

// ---------------------------------------------------------------------------
// SINGLE-PASS attention, QBLK=128, KVBLK=64, 4 waves; wave owns 32 q rows as
// TWO j-halves so every K/V LDS fragment read feeds 2 MFMAs (halves the LDS
// pipe, the top pipe after r11's VALU diet). Pipelined: QK(kt+1) issues before
// softmax(kt); K ring 3-deep (staged 2 ahead), V 2-deep (1 ahead), ONE barrier
// per kt. No max subtraction (r10/r11 verified); clamp removed (T6 >= 0.145
// everywhere, dead in reference too); rsum on the MFMA pipe via ones-operand;
// kt unrolled by 2 (no s copies); hoisted swizzled offsets. DMA staging from
// pre-swizzled global layouts. Q pre-scaled by 1/8.
__global__ __launch_bounds__(256) void k_attn(
    const bf16_t* __restrict__ qb, const bf16_t* __restrict__ kb,
    const bf16_t* __restrict__ vtb, bf16_t* __restrict__ ob,
    const float* __restrict__ exp_c) {
  __shared__ __align__(16) bf16_t Ks[3][64 * 64];
  __shared__ __align__(16) bf16_t Vs[2][64 * 64];
  int tid = threadIdx.x, lane = tid & 63, wave = tid >> 6;
  int b0 = blockIdx.x;
  int bid = (b0 & 7) * 64 + (b0 >> 3);  // XCD-chunked (512 % 8 == 0)
  int qt = bid & 15, bh = bid >> 4;
  const size_t bho = (size_t)bh * (2048 * 64);
  const bf16_t* Q = qb + bho + (size_t)qt * 128 * 64;  // pre-scaled by 1/8
  const bf16_t* Kp = kb + bho;   // rows pre-XOR-swizzled
  const bf16_t* Vp = vtb + bho;  // gl_lds-linear permuted [64 dh][2048 t]
  int lr = lane & 15, lg = lane >> 4;

  // Q fragments: 2 q-halves x 2 k-halves (registers, whole kernel)
  bf16x8 qa[2][2];
#pragma unroll
  for (int j = 0; j < 2; ++j)
#pragma unroll
    for (int h = 0; h < 2; ++h)
      qa[j][h] = *(const bf16x8*)&Q[(wave * 32 + j * 16 + lr) * 64 + h * 32 + lg * 8];

  float ec[7];
#pragma unroll
  for (int i = 0; i < 7; ++i) ec[i] = exp_c[i];

  // ones fragment for the rsum MFMA
  union { unsigned u[4]; bf16x8 v; } ones;
#pragma unroll
  for (int i = 0; i < 4; ++i) ones.u[i] = 0x3f803f80u;  // bf16 1.0 x2

  // hoisted swizzled LDS byte offsets (shared by QK and PV reads)
  int offA[4], offB[4];
#pragma unroll
  for (int n = 0; n < 4; ++n) {
    int row = n * 16 + lr, sw = (row & 7) << 4;
    offA[n] = (row * 128 + lg * 16) ^ sw;
    offB[n] = (row * 128 + 64 + lg * 16) ^ sw;
  }

  auto STAGE_K = [&](int buf, int kt) {
    bf16_t* lk = &Ks[buf][tid * 8];
    const bf16_t* gk = Kp + (size_t)kt * 4096 + tid * 8;
    gl_lds16(gk, lk);
    gl_lds16(gk + 2048, lk + 2048);
  };
  auto STAGE_V = [&](int buf, int kt) {
    bf16_t* lv = &Vs[buf][tid * 8];
    const bf16_t* gv = Vp + (size_t)(tid >> 3) * 2048 + kt * 64 + (tid & 7) * 8;
    gl_lds16(gv, lv);
    gl_lds16(gv + (size_t)32 * 2048, lv + 2048);
  };

  f32x4 zero = {0.f, 0.f, 0.f, 0.f};
  // QK for both q-halves: 8 K-fragment reads feed 16 MFMAs
  auto qk_tile = [&](const char* kbase, f32x4 (*sout)[4]) {
    __builtin_amdgcn_s_setprio(1);
#pragma unroll
    for (int n = 0; n < 4; ++n) {
      bf16x8 kb0 = *(const bf16x8*)(kbase + offA[n]);
      bf16x8 kb1 = *(const bf16x8*)(kbase + offB[n]);
#pragma unroll
      for (int j = 0; j < 2; ++j)
        sout[j][n] = MFMA16(kb1, qa[j][1], MFMA16(kb0, qa[j][0], zero));
    }
    __builtin_amdgcn_s_setprio(0);
  };

  f32x4 oacc[2][4], oacc_s[2];
#pragma unroll
  for (int j = 0; j < 2; ++j) {
#pragma unroll
    for (int n = 0; n < 4; ++n) oacc[j][n] = zero;
    oacc_s[j] = zero;
  }

  f32x4 sA[2][4], sB[2][4];

  STAGE_K(0, 0);
  STAGE_K(1, 1);
  STAGE_V(0, 0);
  __syncthreads();
  qk_tile((const char*)Ks[0], sA);

  // one pipeline step: consume scur(kt), produce snext(kt+1)
  auto STEP = [&](int kt, f32x4 (*scur)[4], f32x4 (*snext)[4]) {
    if (kt < 30) STAGE_K((kt + 2) % 3, kt + 2);
    if (kt < 31) STAGE_V((kt + 1) & 1, kt + 1);
    if (kt < 31) qk_tile((const char*)Ks[(kt + 1) % 3], snext);
    // ---- softmax(kt): Horner only (clamp dead: T6 >= 0.145 everywhere)
    union { unsigned u[4]; bf16x8 v; } pa[2][2];
#pragma unroll
    for (int j = 0; j < 2; ++j) {
      unsigned pk[4][2];
#pragma unroll
      for (int n = 0; n < 4; ++n) {
        float pf[4];
#pragma unroll
        for (int r = 0; r < 4; ++r) {
          float xv = scur[j][n][r];  // scores pre-scaled via Q*0.125
          float p = ec[6];
#pragma unroll
          for (int i = 5; i >= 0; --i) p = __builtin_fmaf(p, xv, ec[i]);
          pf[r] = p;
        }
        pk[n][0] = pack_bf16(pf[0], pf[1]);
        pk[n][1] = pack_bf16(pf[2], pf[3]);
      }
      pa[j][0].u[0] = pk[0][0]; pa[j][0].u[1] = pk[0][1];
      pa[j][0].u[2] = pk[1][0]; pa[j][0].u[3] = pk[1][1];
      pa[j][1].u[0] = pk[2][0]; pa[j][1].u[1] = pk[2][1];
      pa[j][1].u[2] = pk[3][0]; pa[j][1].u[3] = pk[3][1];
    }
    // ---- PV(kt): 8 V-fragment reads feed 16 MFMAs + rsum on MFMA pipe
    const char* vbase = (const char*)Vs[kt & 1];
    __builtin_amdgcn_s_setprio(1);
#pragma unroll
    for (int dd = 0; dd < 4; ++dd) {
      bf16x8 v0 = *(const bf16x8*)(vbase + offA[dd]);
      bf16x8 v1 = *(const bf16x8*)(vbase + offB[dd]);
#pragma unroll
      for (int j = 0; j < 2; ++j)
        oacc[j][dd] = MFMA16(pa[j][1].v, v1, MFMA16(pa[j][0].v, v0, oacc[j][dd]));
    }
#pragma unroll
    for (int j = 0; j < 2; ++j)
      oacc_s[j] = MFMA16(pa[j][1].v, ones.v, MFMA16(pa[j][0].v, ones.v, oacc_s[j]));
    __builtin_amdgcn_s_setprio(0);
    __syncthreads();
  };

  for (int it = 0; it < 16; ++it) {
    STEP(2 * it, sA, sB);
    STEP(2 * it + 1, sB, sA);
  }

  // oacc_s[j][r] holds rsum for q-row (wave*32 + j*16 + lg*4 + r)
  int b_ = bh >> 3, h_ = bh & 7;
#pragma unroll
  for (int j = 0; j < 2; ++j)
#pragma unroll
    for (int dd = 0; dd < 4; ++dd)
#pragma unroll
      for (int r = 0; r < 4; ++r) {
        int t_ = qt * 128 + wave * 32 + j * 16 + lg * 4 + r;
        int d_ = dd * 16 + lr;
        float val = oacc[j][dd][r] / oacc_s[j][r];
        ob[(((size_t)b_ * 2048 + t_) * 8 + h_) * 64 + d_] = (bf16_t)val;
      }
}

// ---------------------------------------------------------------------------
// Fused residual + LayerNorm (replicates Newton rsqrt exactly: 3 iters from 0.5).
__global__ __launch_bounds__(256) void k_ln(
    const float* __restrict__ xa, const float* __restrict__ xb,
    const float* __restrict__ gamma, const float* __restrict__ beta,
    float* __restrict__ outf, bf16_t* __restrict__ outb) {
  int row = blockIdx.x * 4 + (threadIdx.x >> 6);
  int lane = threadIdx.x & 63;
  const float* pa = xa + (size_t)row * 512;
  const float* pb = xb + (size_t)row * 512;
  float4 a0 = ((const float4*)pa)[lane];
  float4 a1 = ((const float4*)pa)[lane + 64];
  float4 b0 = ((const float4*)pb)[lane];
  float4 b1 = ((const float4*)pb)[lane + 64];
  float x[8] = {a0.x + b0.x, a0.y + b0.y, a0.z + b0.z, a0.w + b0.w,
                a1.x + b1.x, a1.y + b1.y, a1.z + b1.z, a1.w + b1.w};
  float s = 0.f, sq = 0.f;
#pragma unroll
  for (int i = 0; i < 8; ++i) { s += x[i]; sq += x[i] * x[i]; }
#pragma unroll
  for (int off = 1; off < 64; off <<= 1) {
    s += __shfl_xor(s, off);
    sq += __shfl_xor(sq, off);
  }
  float mean = s * (1.f / 512.f);
  float var = sq * (1.f / 512.f) - mean * mean;
  float v = var + 1e-5f;
  float y = 0.5f;
#pragma unroll
  for (int it = 0; it < 3; ++it) y = y * (3.0f - v * y * y) * 0.5f;

  float4 g0 = ((const float4*)gamma)[lane];
  float4 g1 = ((const float4*)gamma)[lane + 64];
  float4 e0 = ((const float4*)beta)[lane];
  float4 e1 = ((const float4*)beta)[lane + 64];
  float o[8];
  o[0] = (x[0] - mean) * y * g0.x + e0.x;
  o[1] = (x[1] - mean) * y * g0.y + e0.y;
  o[2] = (x[2] - mean) * y * g0.z + e0.z;
  o[3] = (x[3] - mean) * y * g0.w + e0.w;
  o[4] = (x[4] - mean) * y * g1.x + e1.x;
  o[5] = (x[5] - mean) * y * g1.y + e1.y;
  o[6] = (x[6] - mean) * y * g1.z + e1.z;
  o[7] = (x[7] - mean) * y * g1.w + e1.w;
  float* po = outf + (size_t)row * 512;
  ((float4*)po)[lane]      = make_float4(o[0], o[1], o[2], o[3]);
  ((float4*)po)[lane + 64] = make_float4(o[4], o[5], o[6], o[7]);
  if (outb) {
    bf16_t* pq = outb + (size_t)row * 512;
    union { bf16_t h[4]; uint2 u; } c0, c1;
    c0.h[0] = (bf16_t)o[0]; c0.h[1] = (bf16_t)o[1]; c0.h[2] = (bf16_t)o[2]; c0.h[3] = (bf16_t)o[3];
    c1.h[0] = (bf16_t)o[4]; c1.h[1] = (bf16_t)o[5]; c1.h[2] = (bf16_t)o[6]; c1.h[3] = (bf16_t)o[7];
    ((uint2*)pq)[lane]      = c0.u;
    ((uint2*)pq)[lane + 64] = c1.u;
  }
}

// ---------------------------------------------------------------------------
extern "C" void kernel_launch(void* const* d_in, const int* in_sizes, int n_in,
                              void* d_out, int out_size, void* d_ws, size_t ws_size,
                              hipStream_t stream) {
  const float* x      = (const float*)d_in[0];
  const float* Wq     = (const float*)d_in[1];
  const float* Wk     = (const float*)d_in[2];
  const float* Wv     = (const float*)d_in[3];
  const float* Wo     = (const float*)d_in[4];
  const float* W1     = (const float*)d_in[5];
  const float* W2     = (const float*)d_in[6];
  const float* g1     = (const float*)d_in[7];
  const float* b1     = (const float*)d_in[8];
  const float* g2     = (const float*)d_in[9];
  const float* b2     = (const float*)d_in[10];
  const float* gelu_c = (const float*)d_in[11];
  const float* exp_c  = (const float*)d_in[12];

  const int M = 8192;  // B*T
  const size_t actBF = (size_t)M * 512 * 2;
  char* p = (char*)d_ws;
  auto carve = [&](size_t bytes) {
    void* r = (void*)p;
    p += (bytes + 255) & ~(size_t)255;
    return r;
  };
  bf16_t* x_bf   = (bf16_t*)carve(actBF);
  bf16_t* q_bf   = (bf16_t*)carve(actBF);
  bf16_t* k_bf   = (bf16_t*)carve(actBF);
  bf16_t* vT_bf  = (bf16_t*)carve(actBF);
  bf16_t* o_bf   = (bf16_t*)carve(actBF);
  bf16_t* h_bf   = (bf16_t*)carve(actBF);
  bf16_t* WqkvT  = (bf16_t*)carve((size_t)1536 * 512 * 2);
  bf16_t* WoT    = (bf16_t*)carve(512 * 512 * 2);
  bf16_t* W1T    = (bf16_t*)carve(512 * 2048 * 2);
  bf16_t* W2T    = (bf16_t*)carve(512 * 2048 * 2);
  bf16_t* g_bf   = (bf16_t*)carve((size_t)M * 2048 * 2);
  float*  proj   = (float*)carve((size_t)M * 512 * 4);
  float*  h_f    = (float*)carve((size_t)M * 512 * 4);
  float*  f2     = proj;  // proj dead after LN1; FFN2 output aliases it

  // merged prep: cvt (4096 blocks) + 6 transposes (768 blocks)
  k_prep<<<4864, 256, 0, stream>>>(x, x_bf, Wq, Wk, Wv, Wo, W1, W2,
                                   WqkvT, WoT, W1T, W2T);

  // fused QKV projection (Q pre-scaled; K/V in attention-ready layouts)
  k_gemm_bt<5, 128><<<dim3(64, 12), 256, 0, stream>>>(
      x_bf, WqkvT, nullptr, q_bf, k_bf, vT_bf, M, 1536, 512, nullptr);

  // attention (single pass, QBLK=128 -> 512 blocks)
  k_attn<<<512, 256, 0, stream>>>(q_bf, k_bf, vT_bf, o_bf, exp_c);

  // output projection
  k_gemm_bt<0, 64><<<dim3(128, 4), 256, 0, stream>>>(
      o_bf, WoT, proj, nullptr, nullptr, nullptr, M, 512, 512, nullptr);

  // LN1
  k_ln<<<2048, 256, 0, stream>>>(x, proj, g1, b1, h_f, h_bf);

  // FFN1: gelu(h @ W1) -> bf16
  k_gemm_bt<4, 128><<<dim3(64, 16), 256, 0, stream>>>(
      h_bf, W1T, nullptr, g_bf, nullptr, nullptr, M, 2048, 512, gelu_c);

  // FFN2
  k_gemm_bt<0, 64><<<dim3(128, 4), 256, 0, stream>>>(
      g_bf, W2T, f2, nullptr, nullptr, nullptr, M, 512, 2048, nullptr);

  // LN2
  k_ln<<<2048, 256, 0, stream>>>(h_f, f2, g2, b2, (float*)d_out, nullptr);
}